// Round 12
// baseline (320.173 us; speedup 1.0000x reference)
//
#include <hip/hip_runtime.h>
#include <hip/hip_bf16.h>

#define H 16
#define DK 64
#define DM 1024
#define LQ 512
#define LK 2048
#define BSZ 4

typedef __hip_bfloat16 bf16;
typedef __attribute__((ext_vector_type(8))) short short8;
typedef __attribute__((ext_vector_type(4))) short short4v;
typedef __attribute__((ext_vector_type(4))) float f32x4;

#define LOG2E 1.44269504f
#define SC2 0.18033688f  // 0.125 * log2(e)

// ---------------- fused converts: q,k,v,Wq,Wk,Wv,Wo -> bf16; pack bias/mask; btabT ----------------
// pkd: masked entries -> sentinel index 900 (btabT[h][900] = -1e9 -> exp2 -> 0)
// btabT: per-head 901 entries, value = (btab - 10) * log2e  (exp2-domain, shift folded)

__global__ __launch_bounds__(256) void fused_cvt(
    const float* __restrict__ q, const float* __restrict__ k, const float* __restrict__ v,
    const int* __restrict__ bidx, const int* __restrict__ msk,
    const float* __restrict__ Wq, const float* __restrict__ Wk,
    const float* __restrict__ Wv, const float* __restrict__ Wo,
    const float* __restrict__ btab,
    bf16* __restrict__ qb, bf16* __restrict__ kb, bf16* __restrict__ vb,
    bf16* __restrict__ Wqb, bf16* __restrict__ Wkb, bf16* __restrict__ Wvb,
    bf16* __restrict__ Wob, short* __restrict__ pkd, float* __restrict__ btabT) {
  const int blk = blockIdx.x, tid = threadIdx.x;
  const float* src;
  bf16* dst;
  int base;
  if (blk < 2048)       { src = q;  dst = qb;  base = blk; }
  else if (blk < 10240) { src = k;  dst = kb;  base = blk - 2048; }
  else if (blk < 18432) { src = v;  dst = vb;  base = blk - 10240; }
  else if (blk < 19456) { src = Wq; dst = Wqb; base = blk - 18432; }
  else if (blk < 20480) { src = Wk; dst = Wkb; base = blk - 19456; }
  else if (blk < 21504) { src = Wv; dst = Wvb; base = blk - 20480; }
  else if (blk < 22528) { src = Wo; dst = Wob; base = blk - 21504; }
  else if (blk < 26624) {
    int i = (blk - 22528) * 1024 + tid * 4;
    int4 a = *reinterpret_cast<const int4*>(bidx + i);
    int4 m = *reinterpret_cast<const int4*>(msk + i);
    short4 r;
    r.x = m.x ? (short)a.x : (short)900;
    r.y = m.y ? (short)a.y : (short)900;
    r.z = m.z ? (short)a.z : (short)900;
    r.w = m.w ? (short)a.w : (short)900;
    *reinterpret_cast<short4*>(pkd + i) = r;
    return;
  } else {
    // bias table: transpose + fold softmax shift (-10) + log2e, append sentinel
    for (int j = tid; j < H * 901; j += 256) {
      int hh = j / 901, i = j - hh * 901;
      btabT[j] = (i == 900) ? -1e9f : (btab[i * H + hh] - 10.0f) * LOG2E;
    }
    return;
  }
  int i = base * 1024 + tid * 4;
  float4 val = *reinterpret_cast<const float4*>(src + i);
  bf16 o0 = __float2bfloat16(val.x), o1 = __float2bfloat16(val.y);
  bf16 o2 = __float2bfloat16(val.z), o3 = __float2bfloat16(val.w);
  short4 pk;
  pk.x = *reinterpret_cast<short*>(&o0);
  pk.y = *reinterpret_cast<short*>(&o1);
  pk.z = *reinterpret_cast<short*>(&o2);
  pk.w = *reinterpret_cast<short*>(&o3);
  *reinterpret_cast<short4*>(reinterpret_cast<short*>(dst) + i) = pk;
}

// ---------------- GEMM body: C[m][n] = sum_k A[m][k]*B[n][k] + bias[n] ----------------
// Single-buffered, BK=64 K-steps + rotate-swizzled staging (round-11 proven:
// bank conflicts 4.98M -> 0, total -11us): LDS[r][seg] = G[r][(seg - r)&7]
// (8 segs of 16B per 128B row). Fragment for global seg g read at LDS seg
// (g + l15)&7 -> 2 lanes/bank-group = free. Frags loaded per-K-half (ks=0,1).
// MODE 0: write bf16 head-interleaved  dst[((b*H+h)*Lrows + l)*64 + d]
// MODE 1: d-major V dst[((b*H+h)*64 + d)*LK + key] (computed transposed in-register)
// MODE 2: write f32 row-major          dst[row*N + col]
// TM: 128 (4 waves as 2x2, 64x64 each) or 64 (4 waves as 1x4, 64x32 each)

__device__ __forceinline__ void g2lds16(const bf16* g, bf16* l) {
  __builtin_amdgcn_global_load_lds(
      (__attribute__((address_space(1))) void*)(g),
      (__attribute__((address_space(3))) void*)(l), 16, 0, 0);
}

template <int MODE, int TM>
__device__ __forceinline__ void gemm_body(bf16* __restrict__ As, bf16* __restrict__ Bs,
                                          const bf16* __restrict__ A,
                                          const bf16* __restrict__ B,
                                          const float* __restrict__ bias,
                                          void* __restrict__ out,
                                          int M, int N, int K, int Lrows,
                                          int bx, int by) {
  constexpr int NT = (TM == 128) ? 4 : 2;
  const int tid = threadIdx.x;
  const int wave = tid >> 6, lane = tid & 63;
  const int quad = lane >> 4, l15 = lane & 15;
  const int rowbase = (TM == 128) ? (wave >> 1) * 64 : 0;
  const int colbase = (TM == 128) ? (wave & 1) * 64 : wave * 32;
  const int rowA0 = bx * TM, colB0 = by * 128;
  // staging geometry: inst covers 8 rows x 8 segs; lane i -> row +(i>>3),
  // LDS seg i&7; global seg ((i&7)-(i>>3))&7  (rotate swizzle, row%8 = i>>3)
  const int sro = lane >> 3;                 // 0..7
  const int sgs = ((lane & 7) - sro) & 7;    // global segment to fetch

  f32x4 acc[4][NT];
  const f32x4 zero = {0.f, 0.f, 0.f, 0.f};
  for (int mt = 0; mt < 4; mt++)
    for (int nt = 0; nt < NT; nt++) acc[mt][nt] = zero;

  for (int k0 = 0; k0 < K; k0 += 64) {
    // stage A: TM rows x 64 cols (TM/32 insts per wave)
    for (int c = 0; c < TM / 32; ++c) {
      int r = wave * (TM / 4) + c * 8;
      g2lds16(A + (size_t)(rowA0 + r + sro) * K + k0 + sgs * 8, As + r * 64);
    }
    // stage B: 128 rows x 64 cols (4 insts per wave)
    for (int c = 0; c < 4; ++c) {
      int r = wave * 32 + c * 8;
      g2lds16(B + (size_t)(colB0 + r + sro) * K + k0 + sgs * 8, Bs + r * 64);
    }
    __syncthreads();
    // two K-halves of 32; frag for global seg g=ks*4+quad at LDS seg (g+l15)&7
    for (int ks = 0; ks < 2; ++ks) {
      short8 af[4], bfr[NT];
      for (int mt = 0; mt < 4; mt++)
        af[mt] = *reinterpret_cast<const short8*>(
            As + (rowbase + mt * 16 + l15) * 64 + (((ks * 4 + quad + l15) & 7) << 3));
      for (int nt = 0; nt < NT; nt++)
        bfr[nt] = *reinterpret_cast<const short8*>(
            Bs + (colbase + nt * 16 + l15) * 64 + (((ks * 4 + quad + l15) & 7) << 3));
      for (int mt = 0; mt < 4; mt++)
        for (int nt = 0; nt < NT; nt++) {
          if (MODE == 1)  // swapped: A-op = W rows (n), B-op = act rows (m=key)
            acc[mt][nt] = __builtin_amdgcn_mfma_f32_16x16x32_bf16(bfr[nt], af[mt], acc[mt][nt], 0, 0, 0);
          else
            acc[mt][nt] = __builtin_amdgcn_mfma_f32_16x16x32_bf16(af[mt], bfr[nt], acc[mt][nt], 0, 0, 0);
        }
    }
    __syncthreads();
  }

  const int bb = (MODE == 2) ? 0 : (rowA0 / Lrows);
  const int lb = (MODE == 2) ? rowA0 : (rowA0 - bb * Lrows);
  if (MODE == 1) {
    // D[row=quad*4+r -> n(d-col)][col=l15 -> m(key)]
    for (int mt = 0; mt < 4; mt++) {
      int key = lb + rowbase + mt * 16 + l15;
      for (int nt = 0; nt < NT; nt++) {
        f32x4 v = acc[mt][nt];
        for (int r = 0; r < 4; r++) {
          int ncol = colB0 + colbase + nt * 16 + quad * 4 + r;
          float bv = bias[ncol];
          int hh = ncol >> 6, d = ncol & 63;
          ((bf16*)out)[((size_t)((bb * H + hh) * DK + d)) * LK + key] =
              __float2bfloat16(v[r] + bv);
        }
      }
    }
    return;
  }
  for (int nt = 0; nt < NT; nt++) {
    int col = colB0 + colbase + nt * 16 + l15;
    float bv = bias[col];
    int hh = col >> 6, d = col & 63;
    for (int mt = 0; mt < 4; mt++) {
      int lrow0 = lb + rowbase + mt * 16 + quad * 4;
      f32x4 v = acc[mt][nt];
      for (int r = 0; r < 4; r++) {
        float val = v[r] + bv;
        if (MODE == 0) {
          ((bf16*)out)[(((size_t)(bb * H + hh) * Lrows + lrow0 + r) << 6) + d] = __float2bfloat16(val);
        } else {
          ((float*)out)[(size_t)(lrow0 + r) * N + col] = val;
        }
      }
    }
  }
}

// Merged Q/K/V projection: one launch, 1280 blocks (K:512, V:512, Q:256).
// XCD-chunked remap: xcd = blk&7 (HW round-robin) owns a contiguous bx-range
// with ALL by values, so each A-activation panel is fetched by exactly ONE
// XCD's L2. LDS 32KB (BK=64) -> 5 blocks/CU.
__global__ __launch_bounds__(256) void proj_qkv(
    const bf16* __restrict__ kb, const bf16* __restrict__ Wkb, const float* __restrict__ bk, bf16* __restrict__ Kh,
    const bf16* __restrict__ vb, const bf16* __restrict__ Wvb, const float* __restrict__ bv, bf16* __restrict__ Vt,
    const bf16* __restrict__ qb, const bf16* __restrict__ Wqb, const float* __restrict__ bq, bf16* __restrict__ Qh) {
  __shared__ __align__(16) bf16 As[128 * 64];
  __shared__ __align__(16) bf16 Bs[128 * 64];
  const int blk = blockIdx.x;
  if (blk < 512) {
    const int xcd = blk & 7, slot = blk >> 3;
    gemm_body<0, 128>(As, Bs, kb, Wkb, bk, (void*)Kh, 8192, 1024, 1024, LK,
                      xcd * 8 + (slot & 7), slot >> 3);
  } else if (blk < 1024) {
    const int i = blk - 512, xcd = i & 7, slot = i >> 3;
    gemm_body<1, 128>(As, Bs, vb, Wvb, bv, (void*)Vt, 8192, 1024, 1024, LK,
                      xcd * 8 + (slot & 7), slot >> 3);
  } else {
    const int i = blk - 1024, xcd = i & 7, slot = i >> 3;
    gemm_body<0, 64>(As, Bs, qb, Wqb, bq, (void*)Qh, 2048, 1024, 1024, LQ,
                     xcd * 4 + (slot & 3), slot >> 2);
  }
}

// Output projection, same XCD-chunked remap. 1-D grid of 256 blocks:
// xcd = blk&7 owns 4 bx rows x all 8 by columns (bijective over 256).
__global__ __launch_bounds__(256) void gemm_o(const bf16* __restrict__ A,
                                              const bf16* __restrict__ B,
                                              const float* __restrict__ bias,
                                              float* __restrict__ out) {
  __shared__ __align__(16) bf16 As[64 * 64];
  __shared__ __align__(16) bf16 Bs[128 * 64];
  const int blk = blockIdx.x, xcd = blk & 7, slot = blk >> 3;
  gemm_body<2, 64>(As, Bs, A, B, bias, (void*)out, 2048, 1024, 1024, LQ,
                   xcd * 4 + (slot & 3), slot >> 2);
}

// ---------------- attention v11: full-key blocks (z=1), direct Ob write ----------------
// Split-K epilogue DELETED: grid (BSZ*H, LQ/128) = 256 blocks, block 512.
// Each block = (bh, 128 q rows, ALL 2048 keys = 32 chunks). Same per-chunk
// structure as attn9 (K/V LDS dbuf, rotate swizzle, 1 barrier/chunk); at the
// end each lane holds the full-range O^T and denom -> normalize in-register
// and write bf16 Ob directly (no Opart/L traffic, no combine kernel).
// XCD locality: all 4 qt-blocks of a bh land on xcd bh&7 (qt stride 64 = 0 mod 8).

__global__ __launch_bounds__(512) void attn11(const bf16* __restrict__ Qh,
                                              const bf16* __restrict__ Kh,
                                              const bf16* __restrict__ Vt,
                                              const short* __restrict__ pkm,
                                              const float* __restrict__ btabT,
                                              bf16* __restrict__ Ob) {
  __shared__ __align__(16) bf16 Kbuf[2][64 * 64];
  __shared__ __align__(16) bf16 Vbuf[2][64 * 64];
  __shared__ float bts[901];
  const int tid = threadIdx.x;
  const int wave = tid >> 6, lane = tid & 63;
  const int quad = lane >> 4, l15 = lane & 15;
  const int bh = blockIdx.x, b = bh >> 4, h = bh & 15;
  const int qt = blockIdx.y;

  for (int i = tid; i < 901; i += 512) bts[i] = btabT[h * 901 + i];

  const int q = qt * 128 + wave * 16 + l15;  // this lane's q (B-operand col)
  short8 qf[2];
  for (int ks = 0; ks < 2; ks++)
    qf[ks] = *reinterpret_cast<const short8*>(
        Qh + ((size_t)bh * LQ + q) * DK + ks * 32 + quad * 8);

  const bf16* kbase = Kh + (size_t)bh * LK * DK;
  const bf16* vbase = Vt + (size_t)bh * DK * LK;
  const short* pkrow = pkm + ((size_t)b * LQ + q) * LK;

  // staging geometry (per wave, 1 inst each for K and V):
  // lane i -> LDS row wave*8 + (i>>3), seg i&7 (lane-linear DMA);
  // row's global seg g = ((i&7) - (i>>3)) & 7   (rotate swizzle, row%8 = i>>3)
  const int srow_off = lane >> 3;                // 0..7
  const int sseg = ((lane & 7) - srow_off) & 7;  // global segment to fetch
  const int srow = wave * 8 + srow_off;          // this lane's staged row

  f32x4 of[4];
  float denom = 0.f;
  const f32x4 zero = {0.f, 0.f, 0.f, 0.f};
  for (int dt = 0; dt < 4; dt++) of[dt] = zero;

  // ---- prologue: stage chunk 0 into buf0, prefetch pk chunk 0 ----
  g2lds16(kbase + (size_t)srow * DK + sseg * 8, &Kbuf[0][(wave * 8) * 64]);
  g2lds16(vbase + (size_t)srow * LK + sseg * 8, &Vbuf[0][(wave * 8) * 64]);
  short4v pkv[4];
  for (int nt = 0; nt < 4; nt++)
    pkv[nt] = *reinterpret_cast<const short4v*>(pkrow + nt * 16 + quad * 4);

  __syncthreads();

  for (int kc = 0; kc < 32; ++kc) {
    const int buf = kc & 1;

    // stage chunk kc+1 into buf^1 (completes at the end-of-iter barrier)
    short4v pk_n[4];
    if (kc < 31) {
      const int key1 = (kc + 1) * 64;
      g2lds16(kbase + (size_t)(key1 + srow) * DK + sseg * 8,
              &Kbuf[buf ^ 1][(wave * 8) * 64]);
      g2lds16(vbase + (size_t)srow * LK + key1 + sseg * 8,
              &Vbuf[buf ^ 1][(wave * 8) * 64]);
      for (int nt = 0; nt < 4; nt++)
        pk_n[nt] = *reinterpret_cast<const short4v*>(pkrow + key1 + nt * 16 + quad * 4);
    }

    // K frags from LDS (swizzled): row = nt*16+l15, global seg ks*4+quad
    // at LDS seg (ks*4+quad+l15)&7
    f32x4 sa[4];
    for (int nt = 0; nt < 4; nt++) sa[nt] = zero;
    for (int nt = 0; nt < 4; nt++)
      for (int ks = 0; ks < 2; ks++) {
        short8 kf = *reinterpret_cast<const short8*>(
            &Kbuf[buf][(nt * 16 + l15) * 64 + (((ks * 4 + quad + l15) & 7) << 3)]);
        sa[nt] = __builtin_amdgcn_mfma_f32_16x16x32_bf16(kf, qf[ks], sa[nt], 0, 0, 0);
      }

    // V frags from LDS (swizzled): row d = dt*16+l15, global seg nt*2+(quad>>1),
    // sub-offset (quad&1)*4 elems -> LDS seg (nt*2+(quad>>1)+l15)&7
    short4v vf[4][4];
    for (int dt = 0; dt < 4; dt++)
      for (int nt = 0; nt < 4; nt++)
        vf[dt][nt] = *reinterpret_cast<const short4v*>(
            &Vbuf[buf][(dt * 16 + l15) * 64 +
                       (((nt * 2 + (quad >> 1) + l15) & 7) << 3) + ((quad & 1) << 2)]);

    // p = exp2(s * 0.125*log2e + bts[idx])  (masked idx=900 -> -1e9 -> 0)
    short4v pf[4];
    for (int nt = 0; nt < 4; nt++) {
      float p[4];
      for (int r = 0; r < 4; r++) {
        float t = fmaf(sa[nt][r], SC2, bts[pkv[nt][r]]);
        p[r] = __builtin_amdgcn_exp2f(t);
      }
      denom += (p[0] + p[1]) + (p[2] + p[3]);
      short4v pk4;
      for (int r = 0; r < 4; r++) {
        bf16 tb = __float2bfloat16(p[r]);
        pk4[r] = *reinterpret_cast<short*>(&tb);
      }
      pf[nt] = pk4;
    }

    // PV: O^T[d][q] += V[d][key] * P^T[key][q]
    for (int dt = 0; dt < 4; dt++)
      for (int nt = 0; nt < 4; nt++)
        of[dt] = __builtin_amdgcn_mfma_f32_16x16x16bf16_1k(vf[dt][nt], pf[nt], of[dt], 0, 0, 0);

    if (kc < 31)
      for (int nt = 0; nt < 4; nt++) pkv[nt] = pk_n[nt];

    __syncthreads();  // staging of buf^1 complete; all reads of buf done
  }

  // cross-quad reduction of the denominator (keys split across quads)
  denom += __shfl_xor(denom, 16, 64);
  denom += __shfl_xor(denom, 32, 64);
  const float inv = 1.f / denom;

  // normalize + write bf16 Ob directly: lane covers q (fixed), d = dt*16+quad*4
  bf16* orow = Ob + ((size_t)(b * LQ + q)) * DM + h * 64;
  for (int dt = 0; dt < 4; dt++) {
    short4 pk;
    bf16 t0 = __float2bfloat16(of[dt][0] * inv);
    bf16 t1 = __float2bfloat16(of[dt][1] * inv);
    bf16 t2 = __float2bfloat16(of[dt][2] * inv);
    bf16 t3 = __float2bfloat16(of[dt][3] * inv);
    pk.x = *reinterpret_cast<short*>(&t0);
    pk.y = *reinterpret_cast<short*>(&t1);
    pk.z = *reinterpret_cast<short*>(&t2);
    pk.w = *reinterpret_cast<short*>(&t3);
    *reinterpret_cast<short4*>(orow + dt * 16 + quad * 4) = pk;
  }
}

// ---------------- launcher ----------------

extern "C" void kernel_launch(void* const* d_in, const int* in_sizes, int n_in,
                              void* d_out, int out_size, void* d_ws, size_t ws_size,
                              hipStream_t stream) {
  const float* q = (const float*)d_in[0];
  const float* k = (const float*)d_in[1];
  const float* v = (const float*)d_in[2];
  const int* bidx = (const int*)d_in[3];
  const int* mask = (const int*)d_in[4];
  const float* Wq = (const float*)d_in[5];
  const float* bq = (const float*)d_in[6];
  const float* Wk = (const float*)d_in[7];
  const float* bk = (const float*)d_in[8];
  const float* Wv = (const float*)d_in[9];
  const float* bv = (const float*)d_in[10];
  const float* Wo = (const float*)d_in[11];
  const float* bo = (const float*)d_in[12];
  const float* btab = (const float*)d_in[13];

  char* ws = (char*)d_ws;
  bf16* qb  = (bf16*)(ws + 0);
  bf16* kb  = (bf16*)(ws + 4194304);
  bf16* vb  = (bf16*)(ws + 20971520);
  bf16* Wqb = (bf16*)(ws + 37748736);
  bf16* Wkb = (bf16*)(ws + 39845888);
  bf16* Wvb = (bf16*)(ws + 41943040);
  bf16* Wob = (bf16*)(ws + 44040192);
  bf16* Qh  = (bf16*)(ws + 46137344);
  bf16* Kh  = (bf16*)(ws + 50331648);
  bf16* Vt  = (bf16*)(ws + 67108864);
  short* pkd = (short*)(ws + 83886080);
  // btabT in the former Ob region (written by fused_cvt, read by attn11;
  // nothing overwrites it now that combine/Opart are deleted).
  float* btabT = (float*)(ws + 92274688);      // 57,664 B
  // Ob overlays the qb slot (qb dead after proj_qkv; attn11 writes Ob after
  // proj completes — stream-ordered, exact size match 4,194,304 B).
  bf16* Ob = (bf16*)(ws + 0);
  (void)ws_size; (void)in_sizes; (void)n_in; (void)out_size;

  hipLaunchKernelGGL(fused_cvt, dim3(26625), dim3(256), 0, stream,
                     q, k, v, bidx, mask, Wq, Wk, Wv, Wo, btab,
                     qb, kb, vb, Wqb, Wkb, Wvb, Wob, pkd, btabT);

  hipLaunchKernelGGL(proj_qkv, dim3(1280), dim3(256), 0, stream,
                     kb, Wkb, bk, Kh, vb, Wvb, bv, Vt, qb, Wqb, bq, Qh);

  hipLaunchKernelGGL(attn11, dim3(BSZ * H, LQ / 128), dim3(512), 0, stream,
                     Qh, Kh, Vt, pkd, btabT, Ob);

  hipLaunchKernelGGL(gemm_o, dim3(256), dim3(256), 0, stream,
                     Ob, Wob, bo, (float*)d_out);
}

// Round 13
// 310.384 us; speedup vs baseline: 1.0315x; 1.0315x over previous
//
#include <hip/hip_runtime.h>
#include <hip/hip_bf16.h>

#define H 16
#define DK 64
#define DM 1024
#define LQ 512
#define LK 2048
#define BSZ 4

typedef __hip_bfloat16 bf16;
typedef __attribute__((ext_vector_type(8))) short short8;
typedef __attribute__((ext_vector_type(4))) short short4v;
typedef __attribute__((ext_vector_type(4))) float f32x4;

#define LOG2E 1.44269504f
#define SC2 0.18033688f  // 0.125 * log2(e)

// ---------------- fused converts: q,k,v,Wq,Wk,Wv,Wo -> bf16; pack bias/mask; btabT ----------------
// pkd: masked entries -> sentinel index 900 (btabT[h][900] = -1e9 -> exp2 -> 0)
// btabT: per-head 901 entries, value = (btab - 10) * log2e  (exp2-domain, shift folded)

__global__ __launch_bounds__(256) void fused_cvt(
    const float* __restrict__ q, const float* __restrict__ k, const float* __restrict__ v,
    const int* __restrict__ bidx, const int* __restrict__ msk,
    const float* __restrict__ Wq, const float* __restrict__ Wk,
    const float* __restrict__ Wv, const float* __restrict__ Wo,
    const float* __restrict__ btab,
    bf16* __restrict__ qb, bf16* __restrict__ kb, bf16* __restrict__ vb,
    bf16* __restrict__ Wqb, bf16* __restrict__ Wkb, bf16* __restrict__ Wvb,
    bf16* __restrict__ Wob, short* __restrict__ pkd, float* __restrict__ btabT) {
  const int blk = blockIdx.x, tid = threadIdx.x;
  const float* src;
  bf16* dst;
  int base;
  if (blk < 2048)       { src = q;  dst = qb;  base = blk; }
  else if (blk < 10240) { src = k;  dst = kb;  base = blk - 2048; }
  else if (blk < 18432) { src = v;  dst = vb;  base = blk - 10240; }
  else if (blk < 19456) { src = Wq; dst = Wqb; base = blk - 18432; }
  else if (blk < 20480) { src = Wk; dst = Wkb; base = blk - 19456; }
  else if (blk < 21504) { src = Wv; dst = Wvb; base = blk - 20480; }
  else if (blk < 22528) { src = Wo; dst = Wob; base = blk - 21504; }
  else if (blk < 26624) {
    int i = (blk - 22528) * 1024 + tid * 4;
    int4 a = *reinterpret_cast<const int4*>(bidx + i);
    int4 m = *reinterpret_cast<const int4*>(msk + i);
    short4 r;
    r.x = m.x ? (short)a.x : (short)900;
    r.y = m.y ? (short)a.y : (short)900;
    r.z = m.z ? (short)a.z : (short)900;
    r.w = m.w ? (short)a.w : (short)900;
    *reinterpret_cast<short4*>(pkd + i) = r;
    return;
  } else {
    // bias table: transpose + fold softmax shift (-10) + log2e, append sentinel
    for (int j = tid; j < H * 901; j += 256) {
      int hh = j / 901, i = j - hh * 901;
      btabT[j] = (i == 900) ? -1e9f : (btab[i * H + hh] - 10.0f) * LOG2E;
    }
    return;
  }
  int i = base * 1024 + tid * 4;
  float4 val = *reinterpret_cast<const float4*>(src + i);
  bf16 o0 = __float2bfloat16(val.x), o1 = __float2bfloat16(val.y);
  bf16 o2 = __float2bfloat16(val.z), o3 = __float2bfloat16(val.w);
  short4 pk;
  pk.x = *reinterpret_cast<short*>(&o0);
  pk.y = *reinterpret_cast<short*>(&o1);
  pk.z = *reinterpret_cast<short*>(&o2);
  pk.w = *reinterpret_cast<short*>(&o3);
  *reinterpret_cast<short4*>(reinterpret_cast<short*>(dst) + i) = pk;
}

// ---------------- GEMM body: C[m][n] = sum_k A[m][k]*B[n][k] + bias[n] ----------------
// Single-buffered, BK=64 K-steps + rotate-swizzled staging (round-11 proven:
// bank conflicts 4.98M -> 0, total -11us): LDS[r][seg] = G[r][(seg - r)&7]
// (8 segs of 16B per 128B row). Fragment for global seg g read at LDS seg
// (g + l15)&7 -> 2 lanes/bank-group = free. Frags loaded per-K-half (ks=0,1).
// MODE 0: write bf16 head-interleaved  dst[((b*H+h)*Lrows + l)*64 + d]
// MODE 1: d-major V dst[((b*H+h)*64 + d)*LK + key] (computed transposed in-register)
// MODE 2: write f32 row-major          dst[row*N + col]
// TM: 128 (4 waves as 2x2, 64x64 each) or 64 (4 waves as 1x4, 64x32 each)

__device__ __forceinline__ void g2lds16(const bf16* g, bf16* l) {
  __builtin_amdgcn_global_load_lds(
      (__attribute__((address_space(1))) void*)(g),
      (__attribute__((address_space(3))) void*)(l), 16, 0, 0);
}

template <int MODE, int TM>
__device__ __forceinline__ void gemm_body(bf16* __restrict__ As, bf16* __restrict__ Bs,
                                          const bf16* __restrict__ A,
                                          const bf16* __restrict__ B,
                                          const float* __restrict__ bias,
                                          void* __restrict__ out,
                                          int M, int N, int K, int Lrows,
                                          int bx, int by) {
  constexpr int NT = (TM == 128) ? 4 : 2;
  const int tid = threadIdx.x;
  const int wave = tid >> 6, lane = tid & 63;
  const int quad = lane >> 4, l15 = lane & 15;
  const int rowbase = (TM == 128) ? (wave >> 1) * 64 : 0;
  const int colbase = (TM == 128) ? (wave & 1) * 64 : wave * 32;
  const int rowA0 = bx * TM, colB0 = by * 128;
  // staging geometry: inst covers 8 rows x 8 segs; lane i -> row +(i>>3),
  // LDS seg i&7; global seg ((i&7)-(i>>3))&7  (rotate swizzle, row%8 = i>>3)
  const int sro = lane >> 3;                 // 0..7
  const int sgs = ((lane & 7) - sro) & 7;    // global segment to fetch

  f32x4 acc[4][NT];
  const f32x4 zero = {0.f, 0.f, 0.f, 0.f};
  for (int mt = 0; mt < 4; mt++)
    for (int nt = 0; nt < NT; nt++) acc[mt][nt] = zero;

  for (int k0 = 0; k0 < K; k0 += 64) {
    // stage A: TM rows x 64 cols (TM/32 insts per wave)
    for (int c = 0; c < TM / 32; ++c) {
      int r = wave * (TM / 4) + c * 8;
      g2lds16(A + (size_t)(rowA0 + r + sro) * K + k0 + sgs * 8, As + r * 64);
    }
    // stage B: 128 rows x 64 cols (4 insts per wave)
    for (int c = 0; c < 4; ++c) {
      int r = wave * 32 + c * 8;
      g2lds16(B + (size_t)(colB0 + r + sro) * K + k0 + sgs * 8, Bs + r * 64);
    }
    __syncthreads();
    // two K-halves of 32; frag for global seg g=ks*4+quad at LDS seg (g+l15)&7
    for (int ks = 0; ks < 2; ++ks) {
      short8 af[4], bfr[NT];
      for (int mt = 0; mt < 4; mt++)
        af[mt] = *reinterpret_cast<const short8*>(
            As + (rowbase + mt * 16 + l15) * 64 + (((ks * 4 + quad + l15) & 7) << 3));
      for (int nt = 0; nt < NT; nt++)
        bfr[nt] = *reinterpret_cast<const short8*>(
            Bs + (colbase + nt * 16 + l15) * 64 + (((ks * 4 + quad + l15) & 7) << 3));
      for (int mt = 0; mt < 4; mt++)
        for (int nt = 0; nt < NT; nt++) {
          if (MODE == 1)  // swapped: A-op = W rows (n), B-op = act rows (m=key)
            acc[mt][nt] = __builtin_amdgcn_mfma_f32_16x16x32_bf16(bfr[nt], af[mt], acc[mt][nt], 0, 0, 0);
          else
            acc[mt][nt] = __builtin_amdgcn_mfma_f32_16x16x32_bf16(af[mt], bfr[nt], acc[mt][nt], 0, 0, 0);
        }
    }
    __syncthreads();
  }

  const int bb = (MODE == 2) ? 0 : (rowA0 / Lrows);
  const int lb = (MODE == 2) ? rowA0 : (rowA0 - bb * Lrows);
  if (MODE == 1) {
    // D[row=quad*4+r -> n(d-col)][col=l15 -> m(key)]
    for (int mt = 0; mt < 4; mt++) {
      int key = lb + rowbase + mt * 16 + l15;
      for (int nt = 0; nt < NT; nt++) {
        f32x4 v = acc[mt][nt];
        for (int r = 0; r < 4; r++) {
          int ncol = colB0 + colbase + nt * 16 + quad * 4 + r;
          float bv = bias[ncol];
          int hh = ncol >> 6, d = ncol & 63;
          ((bf16*)out)[((size_t)((bb * H + hh) * DK + d)) * LK + key] =
              __float2bfloat16(v[r] + bv);
        }
      }
    }
    return;
  }
  for (int nt = 0; nt < NT; nt++) {
    int col = colB0 + colbase + nt * 16 + l15;
    float bv = bias[col];
    int hh = col >> 6, d = col & 63;
    for (int mt = 0; mt < 4; mt++) {
      int lrow0 = lb + rowbase + mt * 16 + quad * 4;
      f32x4 v = acc[mt][nt];
      for (int r = 0; r < 4; r++) {
        float val = v[r] + bv;
        if (MODE == 0) {
          ((bf16*)out)[(((size_t)(bb * H + hh) * Lrows + lrow0 + r) << 6) + d] = __float2bfloat16(val);
        } else {
          ((float*)out)[(size_t)(lrow0 + r) * N + col] = val;
        }
      }
    }
  }
}

// Merged Q/K/V projection: one launch, 1280 blocks (K:512, V:512, Q:256).
// XCD-chunked remap: xcd = blk&7 (HW round-robin) owns a contiguous bx-range
// with ALL by values, so each A-activation panel is fetched by exactly ONE
// XCD's L2. LDS 32KB (BK=64) -> 5 blocks/CU.
__global__ __launch_bounds__(256) void proj_qkv(
    const bf16* __restrict__ kb, const bf16* __restrict__ Wkb, const float* __restrict__ bk, bf16* __restrict__ Kh,
    const bf16* __restrict__ vb, const bf16* __restrict__ Wvb, const float* __restrict__ bv, bf16* __restrict__ Vt,
    const bf16* __restrict__ qb, const bf16* __restrict__ Wqb, const float* __restrict__ bq, bf16* __restrict__ Qh) {
  __shared__ __align__(16) bf16 As[128 * 64];
  __shared__ __align__(16) bf16 Bs[128 * 64];
  const int blk = blockIdx.x;
  if (blk < 512) {
    const int xcd = blk & 7, slot = blk >> 3;
    gemm_body<0, 128>(As, Bs, kb, Wkb, bk, (void*)Kh, 8192, 1024, 1024, LK,
                      xcd * 8 + (slot & 7), slot >> 3);
  } else if (blk < 1024) {
    const int i = blk - 512, xcd = i & 7, slot = i >> 3;
    gemm_body<1, 128>(As, Bs, vb, Wvb, bv, (void*)Vt, 8192, 1024, 1024, LK,
                      xcd * 8 + (slot & 7), slot >> 3);
  } else {
    const int i = blk - 1024, xcd = i & 7, slot = i >> 3;
    gemm_body<0, 64>(As, Bs, qb, Wqb, bq, (void*)Qh, 2048, 1024, 1024, LQ,
                     xcd * 4 + (slot & 3), slot >> 2);
  }
}

// Output projection, same XCD-chunked remap. 1-D grid of 256 blocks:
// xcd = blk&7 owns 4 bx rows x all 8 by columns (bijective over 256).
__global__ __launch_bounds__(256) void gemm_o(const bf16* __restrict__ A,
                                              const bf16* __restrict__ B,
                                              const float* __restrict__ bias,
                                              float* __restrict__ out) {
  __shared__ __align__(16) bf16 As[64 * 64];
  __shared__ __align__(16) bf16 Bs[128 * 64];
  const int blk = blockIdx.x, xcd = blk & 7, slot = blk >> 3;
  gemm_body<2, 64>(As, Bs, A, B, bias, (void*)out, 2048, 1024, 1024, LQ,
                   xcd * 4 + (slot & 3), slot >> 2);
}

// ---------------- attention v13: KVBLK=128 (2 sub-tiles per barrier) over attn9 ----------------
// Revert of round-12's z=1 (occupancy halved -> +17us). Base = attn9 (z=2,
// 8 waves, 128 q rows, K/V dbuf + rotate swizzle) with the round-11 GEMM
// lesson applied: amortize the vmcnt(0)-drain barrier over 2x keys.
// Each chunk = 128 keys = two 64-key SUB-TILES in the proven [64][64] layout;
// computed sequentially reusing the same registers (VGPR flat), ONE barrier
// per 128 keys -> 8 barriers/block instead of 16.
// LDS: K 2buf x 2sub x 8KB + V same + bts = 69KB -> 2 blocks/CU (unchanged).

__global__ __launch_bounds__(512) void attn13(const bf16* __restrict__ Qh,
                                              const bf16* __restrict__ Kh,
                                              const bf16* __restrict__ Vt,
                                              const short* __restrict__ pkm,
                                              const float* __restrict__ btabT,
                                              float* __restrict__ Opart,
                                              float* __restrict__ L) {
  __shared__ __align__(16) bf16 Kbuf[2][2][64 * 64];
  __shared__ __align__(16) bf16 Vbuf[2][2][64 * 64];
  __shared__ float bts[901];
  const int tid = threadIdx.x;
  const int wave = tid >> 6, lane = tid & 63;
  const int quad = lane >> 4, l15 = lane & 15;
  const int bh = blockIdx.x, b = bh >> 4, h = bh & 15;
  const int qt = blockIdx.y, z = blockIdx.z;
  const int key_base = z * 1024;

  for (int i = tid; i < 901; i += 512) bts[i] = btabT[h * 901 + i];

  const int q = qt * 128 + wave * 16 + l15;  // this lane's q (B-operand col)
  short8 qf[2];
  for (int ks = 0; ks < 2; ks++)
    qf[ks] = *reinterpret_cast<const short8*>(
        Qh + ((size_t)bh * LQ + q) * DK + ks * 32 + quad * 8);

  const bf16* kbase = Kh + ((size_t)bh * LK + key_base) * DK;
  const bf16* vbase = Vt + ((size_t)bh * DK) * LK + key_base;
  const short* pkrow = pkm + ((size_t)b * LQ + q) * LK + key_base;

  // staging geometry: lane i -> LDS row-offset (i>>3), seg i&7 (lane-linear
  // DMA); row's global seg g = ((i&7) - (i>>3)) & 7 (rotate swizzle, row%8=i>>3)
  const int srow_off = lane >> 3;                // 0..7
  const int sseg = ((lane & 7) - srow_off) & 7;  // global segment to fetch

  f32x4 of[4];
  float denom = 0.f;
  const f32x4 zero = {0.f, 0.f, 0.f, 0.f};
  for (int dt = 0; dt < 4; dt++) of[dt] = zero;

  // ---- prologue: stage chunk 0 (128 keys, both subs), prefetch pk chunk 0 ----
  // K: 128 key-rows; wave covers rows wave*16 + c*8 + (0..7), sub = r>>6
  for (int c = 0; c < 2; c++) {
    int r = wave * 16 + c * 8;
    g2lds16(kbase + (size_t)(r + srow_off) * DK + sseg * 8,
            &Kbuf[0][r >> 6][(r & 63) * 64]);
  }
  // V: per sub, 64 d-rows; wave covers d-rows wave*8 + (0..7)
  for (int s = 0; s < 2; s++)
    g2lds16(vbase + (size_t)(wave * 8 + srow_off) * LK + s * 64 + sseg * 8,
            &Vbuf[0][s][(wave * 8) * 64]);
  short4v pkv[2][4];
  for (int s = 0; s < 2; s++)
    for (int nt = 0; nt < 4; nt++)
      pkv[s][nt] = *reinterpret_cast<const short4v*>(pkrow + s * 64 + nt * 16 + quad * 4);

  __syncthreads();

  for (int kc = 0; kc < 8; ++kc) {
    const int buf = kc & 1;

    // stage chunk kc+1 into buf^1 (completes at the end-of-iter barrier)
    short4v pk_n[2][4];
    if (kc < 7) {
      const int key1 = (kc + 1) * 128;
      for (int c = 0; c < 2; c++) {
        int r = wave * 16 + c * 8;
        g2lds16(kbase + (size_t)(key1 + r + srow_off) * DK + sseg * 8,
                &Kbuf[buf ^ 1][r >> 6][(r & 63) * 64]);
      }
      for (int s = 0; s < 2; s++)
        g2lds16(vbase + (size_t)(wave * 8 + srow_off) * LK + key1 + s * 64 + sseg * 8,
                &Vbuf[buf ^ 1][s][(wave * 8) * 64]);
      for (int s = 0; s < 2; s++)
        for (int nt = 0; nt < 4; nt++)
          pk_n[s][nt] = *reinterpret_cast<const short4v*>(
              pkrow + key1 + s * 64 + nt * 16 + quad * 4);
    }

    // two 64-key sub-tiles, sequential (registers reused per sub)
    for (int s = 0; s < 2; s++) {
      // K frags from LDS (swizzled): row = nt*16+l15, global seg ks*4+quad
      // at LDS seg (ks*4+quad+l15)&7
      f32x4 sa[4];
      for (int nt = 0; nt < 4; nt++) sa[nt] = zero;
      for (int nt = 0; nt < 4; nt++)
        for (int ks = 0; ks < 2; ks++) {
          short8 kf = *reinterpret_cast<const short8*>(
              &Kbuf[buf][s][(nt * 16 + l15) * 64 + (((ks * 4 + quad + l15) & 7) << 3)]);
          sa[nt] = __builtin_amdgcn_mfma_f32_16x16x32_bf16(kf, qf[ks], sa[nt], 0, 0, 0);
        }

      // V frags from LDS (swizzled): row d = dt*16+l15, global seg nt*2+(quad>>1),
      // sub-offset (quad&1)*4 elems -> LDS seg (nt*2+(quad>>1)+l15)&7
      short4v vf[4][4];
      for (int dt = 0; dt < 4; dt++)
        for (int nt = 0; nt < 4; nt++)
          vf[dt][nt] = *reinterpret_cast<const short4v*>(
              &Vbuf[buf][s][(dt * 16 + l15) * 64 +
                            (((nt * 2 + (quad >> 1) + l15) & 7) << 3) + ((quad & 1) << 2)]);

      // p = exp2(s * 0.125*log2e + bts[idx])  (masked idx=900 -> -1e9 -> 0)
      short4v pf[4];
      for (int nt = 0; nt < 4; nt++) {
        float p[4];
        for (int r = 0; r < 4; r++) {
          float t = fmaf(sa[nt][r], SC2, bts[pkv[s][nt][r]]);
          p[r] = __builtin_amdgcn_exp2f(t);
        }
        denom += (p[0] + p[1]) + (p[2] + p[3]);
        short4v pk4;
        for (int r = 0; r < 4; r++) {
          bf16 tb = __float2bfloat16(p[r]);
          pk4[r] = *reinterpret_cast<short*>(&tb);
        }
        pf[nt] = pk4;
      }

      // PV: O^T[d][q] += V[d][key] * P^T[key][q]
      for (int dt = 0; dt < 4; dt++)
        for (int nt = 0; nt < 4; nt++)
          of[dt] = __builtin_amdgcn_mfma_f32_16x16x16bf16_1k(vf[dt][nt], pf[nt], of[dt], 0, 0, 0);
    }

    if (kc < 7)
      for (int s = 0; s < 2; s++)
        for (int nt = 0; nt < 4; nt++) pkv[s][nt] = pk_n[s][nt];

    __syncthreads();  // staging of buf^1 complete; all reads of buf done
  }

  // cross-quad reduction of the denominator (keys split across quads)
  denom += __shfl_xor(denom, 16, 64);
  denom += __shfl_xor(denom, 32, 64);

  size_t rowi = ((size_t)z * 64 + bh) * LQ + q;
  float* orow = Opart + rowi * 64;
  for (int dt = 0; dt < 4; dt++)
    *reinterpret_cast<f32x4*>(orow + dt * 16 + quad * 4) = of[dt];
  if (quad == 0) L[rowi] = denom;
}

// combine the two split-K halves -> bf16 Ob (plain sums; same fixed shift)
__global__ __launch_bounds__(256) void attn_combine(const float* __restrict__ Opart,
                                                    const float* __restrict__ L,
                                                    bf16* __restrict__ Ob) {
  int t = blockIdx.x * 256 + threadIdx.x;  // over 2M/4
  int g = t * 4;
  int row = g >> 6, d0 = g & 63;
  float l = L[row] + L[32768 + row];
  float4 o;
  float4 p0 = *reinterpret_cast<const float4*>(Opart + ((size_t)row << 6) + d0);
  float4 p1 = *reinterpret_cast<const float4*>(Opart + (((size_t)32768 + row) << 6) + d0);
  o.x = p0.x + p1.x; o.y = p0.y + p1.y; o.z = p0.z + p1.z; o.w = p0.w + p1.w;
  float inv = 1.f / l;
  bf16 t0 = __float2bfloat16(o.x * inv), t1 = __float2bfloat16(o.y * inv);
  bf16 t2 = __float2bfloat16(o.z * inv), t3 = __float2bfloat16(o.w * inv);
  short4 pk;
  pk.x = *reinterpret_cast<short*>(&t0);
  pk.y = *reinterpret_cast<short*>(&t1);
  pk.z = *reinterpret_cast<short*>(&t2);
  pk.w = *reinterpret_cast<short*>(&t3);
  int bh = row >> 9, qq = row & 511, b_ = bh >> 4, h = bh & 15;
  *reinterpret_cast<short4*>(Ob + ((size_t)(b_ * LQ + qq)) * DM + h * 64 + d0) = pk;
}

// ---------------- launcher ----------------

extern "C" void kernel_launch(void* const* d_in, const int* in_sizes, int n_in,
                              void* d_out, int out_size, void* d_ws, size_t ws_size,
                              hipStream_t stream) {
  const float* q = (const float*)d_in[0];
  const float* k = (const float*)d_in[1];
  const float* v = (const float*)d_in[2];
  const int* bidx = (const int*)d_in[3];
  const int* mask = (const int*)d_in[4];
  const float* Wq = (const float*)d_in[5];
  const float* bq = (const float*)d_in[6];
  const float* Wk = (const float*)d_in[7];
  const float* bk = (const float*)d_in[8];
  const float* Wv = (const float*)d_in[9];
  const float* bv = (const float*)d_in[10];
  const float* Wo = (const float*)d_in[11];
  const float* bo = (const float*)d_in[12];
  const float* btab = (const float*)d_in[13];

  char* ws = (char*)d_ws;
  bf16* qb  = (bf16*)(ws + 0);
  bf16* kb  = (bf16*)(ws + 4194304);
  bf16* vb  = (bf16*)(ws + 20971520);
  bf16* Wqb = (bf16*)(ws + 37748736);
  bf16* Wkb = (bf16*)(ws + 39845888);
  bf16* Wvb = (bf16*)(ws + 41943040);
  bf16* Wob = (bf16*)(ws + 44040192);
  bf16* Qh  = (bf16*)(ws + 46137344);
  bf16* Kh  = (bf16*)(ws + 50331648);
  bf16* Vt  = (bf16*)(ws + 67108864);
  short* pkd = (short*)(ws + 83886080);
  bf16* Ob  = (bf16*)(ws + 92274688);
  // btabT overlays the START of the Ob region: written by fused_cvt, read by
  // attn13, and only THEN overwritten by attn_combine (stream-ordered — safe).
  float* btabT = (float*)(ws + 92274688);      // 57,664 B
  // Opart/L overlay qb/kb region (dead after the projection GEMMs)
  float* Opart = (float*)(ws + 0);             // 16,777,216 B (2 z-halves)
  float* L     = (float*)(ws + 16777216);      //    262,144 B
  (void)ws_size; (void)in_sizes; (void)n_in; (void)out_size;

  hipLaunchKernelGGL(fused_cvt, dim3(26625), dim3(256), 0, stream,
                     q, k, v, bidx, mask, Wq, Wk, Wv, Wo, btab,
                     qb, kb, vb, Wqb, Wkb, Wvb, Wob, pkd, btabT);

  hipLaunchKernelGGL(proj_qkv, dim3(1280), dim3(256), 0, stream,
                     kb, Wkb, bk, Kh, vb, Wvb, bv, Vt, qb, Wqb, bq, Qh);

  hipLaunchKernelGGL(attn13, dim3(BSZ * H, LQ / 128, 2), dim3(512), 0, stream,
                     Qh, Kh, Vt, pkd, btabT, Opart, L);
  hipLaunchKernelGGL(attn_combine, dim3(2048), dim3(256), 0, stream,
                     Opart, L, Ob);

  hipLaunchKernelGGL(gemm_o, dim3(256), dim3(256), 0, stream,
                     Ob, Wob, bo, (float*)d_out);
}

// Round 14
// 304.770 us; speedup vs baseline: 1.0505x; 1.0184x over previous
//
#include <hip/hip_runtime.h>
#include <hip/hip_bf16.h>

#define H 16
#define DK 64
#define DM 1024
#define LQ 512
#define LK 2048
#define BSZ 4

typedef __hip_bfloat16 bf16;
typedef __attribute__((ext_vector_type(8))) short short8;
typedef __attribute__((ext_vector_type(4))) short short4v;
typedef __attribute__((ext_vector_type(4))) float f32x4;

#define LOG2E 1.44269504f
#define SC2 0.18033688f  // 0.125 * log2(e)

// ---------------- fused converts: q,k,v,Wq,Wk,Wv,Wo -> bf16; pack bias/mask; btabT ----------------
// pkd: masked entries -> sentinel index 900 (btabT[h][900] = -1e9 -> exp2 -> 0)
// btabT: per-head 901 entries, value = (btab - 10) * log2e  (exp2-domain, shift folded)

__global__ __launch_bounds__(256) void fused_cvt(
    const float* __restrict__ q, const float* __restrict__ k, const float* __restrict__ v,
    const int* __restrict__ bidx, const int* __restrict__ msk,
    const float* __restrict__ Wq, const float* __restrict__ Wk,
    const float* __restrict__ Wv, const float* __restrict__ Wo,
    const float* __restrict__ btab,
    bf16* __restrict__ qb, bf16* __restrict__ kb, bf16* __restrict__ vb,
    bf16* __restrict__ Wqb, bf16* __restrict__ Wkb, bf16* __restrict__ Wvb,
    bf16* __restrict__ Wob, short* __restrict__ pkd, float* __restrict__ btabT) {
  const int blk = blockIdx.x, tid = threadIdx.x;
  const float* src;
  bf16* dst;
  int base;
  if (blk < 2048)       { src = q;  dst = qb;  base = blk; }
  else if (blk < 10240) { src = k;  dst = kb;  base = blk - 2048; }
  else if (blk < 18432) { src = v;  dst = vb;  base = blk - 10240; }
  else if (blk < 19456) { src = Wq; dst = Wqb; base = blk - 18432; }
  else if (blk < 20480) { src = Wk; dst = Wkb; base = blk - 19456; }
  else if (blk < 21504) { src = Wv; dst = Wvb; base = blk - 20480; }
  else if (blk < 22528) { src = Wo; dst = Wob; base = blk - 21504; }
  else if (blk < 26624) {
    int i = (blk - 22528) * 1024 + tid * 4;
    int4 a = *reinterpret_cast<const int4*>(bidx + i);
    int4 m = *reinterpret_cast<const int4*>(msk + i);
    short4 r;
    r.x = m.x ? (short)a.x : (short)900;
    r.y = m.y ? (short)a.y : (short)900;
    r.z = m.z ? (short)a.z : (short)900;
    r.w = m.w ? (short)a.w : (short)900;
    *reinterpret_cast<short4*>(pkd + i) = r;
    return;
  } else {
    // bias table: transpose + fold softmax shift (-10) + log2e, append sentinel
    for (int j = tid; j < H * 901; j += 256) {
      int hh = j / 901, i = j - hh * 901;
      btabT[j] = (i == 900) ? -1e9f : (btab[i * H + hh] - 10.0f) * LOG2E;
    }
    return;
  }
  int i = base * 1024 + tid * 4;
  float4 val = *reinterpret_cast<const float4*>(src + i);
  bf16 o0 = __float2bfloat16(val.x), o1 = __float2bfloat16(val.y);
  bf16 o2 = __float2bfloat16(val.z), o3 = __float2bfloat16(val.w);
  short4 pk;
  pk.x = *reinterpret_cast<short*>(&o0);
  pk.y = *reinterpret_cast<short*>(&o1);
  pk.z = *reinterpret_cast<short*>(&o2);
  pk.w = *reinterpret_cast<short*>(&o3);
  *reinterpret_cast<short4*>(reinterpret_cast<short*>(dst) + i) = pk;
}

// ---------------- GEMM body: C[m][n] = sum_k A[m][k]*B[n][k] + bias[n] ----------------
// Single-buffered, BK=64 K-steps + rotate-swizzled staging (round-11 proven:
// bank conflicts 4.98M -> 0, total -11us): LDS[r][seg] = G[r][(seg - r)&7]
// (8 segs of 16B per 128B row). Fragment for global seg g read at LDS seg
// (g + l15)&7 -> 2 lanes/bank-group = free. Frags loaded per-K-half (ks=0,1).
// MODE 0: write bf16 head-interleaved  dst[((b*H+h)*Lrows + l)*64 + d]
// MODE 1: d-major V dst[((b*H+h)*64 + d)*LK + key] (computed transposed in-register)
// MODE 2: write f32 row-major          dst[row*N + col]
// TM: 128 (4 waves as 2x2, 64x64 each) or 64 (4 waves as 1x4, 64x32 each)

__device__ __forceinline__ void g2lds16(const bf16* g, bf16* l) {
  __builtin_amdgcn_global_load_lds(
      (__attribute__((address_space(1))) void*)(g),
      (__attribute__((address_space(3))) void*)(l), 16, 0, 0);
}

template <int MODE, int TM>
__device__ __forceinline__ void gemm_body(bf16* __restrict__ As, bf16* __restrict__ Bs,
                                          const bf16* __restrict__ A,
                                          const bf16* __restrict__ B,
                                          const float* __restrict__ bias,
                                          void* __restrict__ out,
                                          int M, int N, int K, int Lrows,
                                          int bx, int by) {
  constexpr int NT = (TM == 128) ? 4 : 2;
  const int tid = threadIdx.x;
  const int wave = tid >> 6, lane = tid & 63;
  const int quad = lane >> 4, l15 = lane & 15;
  const int rowbase = (TM == 128) ? (wave >> 1) * 64 : 0;
  const int colbase = (TM == 128) ? (wave & 1) * 64 : wave * 32;
  const int rowA0 = bx * TM, colB0 = by * 128;
  // staging geometry: inst covers 8 rows x 8 segs; lane i -> row +(i>>3),
  // LDS seg i&7; global seg ((i&7)-(i>>3))&7  (rotate swizzle, row%8 = i>>3)
  const int sro = lane >> 3;                 // 0..7
  const int sgs = ((lane & 7) - sro) & 7;    // global segment to fetch

  f32x4 acc[4][NT];
  const f32x4 zero = {0.f, 0.f, 0.f, 0.f};
  for (int mt = 0; mt < 4; mt++)
    for (int nt = 0; nt < NT; nt++) acc[mt][nt] = zero;

  for (int k0 = 0; k0 < K; k0 += 64) {
    // stage A: TM rows x 64 cols (TM/32 insts per wave)
    for (int c = 0; c < TM / 32; ++c) {
      int r = wave * (TM / 4) + c * 8;
      g2lds16(A + (size_t)(rowA0 + r + sro) * K + k0 + sgs * 8, As + r * 64);
    }
    // stage B: 128 rows x 64 cols (4 insts per wave)
    for (int c = 0; c < 4; ++c) {
      int r = wave * 32 + c * 8;
      g2lds16(B + (size_t)(colB0 + r + sro) * K + k0 + sgs * 8, Bs + r * 64);
    }
    __syncthreads();
    // two K-halves of 32; frag for global seg g=ks*4+quad at LDS seg (g+l15)&7
    for (int ks = 0; ks < 2; ++ks) {
      short8 af[4], bfr[NT];
      for (int mt = 0; mt < 4; mt++)
        af[mt] = *reinterpret_cast<const short8*>(
            As + (rowbase + mt * 16 + l15) * 64 + (((ks * 4 + quad + l15) & 7) << 3));
      for (int nt = 0; nt < NT; nt++)
        bfr[nt] = *reinterpret_cast<const short8*>(
            Bs + (colbase + nt * 16 + l15) * 64 + (((ks * 4 + quad + l15) & 7) << 3));
      for (int mt = 0; mt < 4; mt++)
        for (int nt = 0; nt < NT; nt++) {
          if (MODE == 1)  // swapped: A-op = W rows (n), B-op = act rows (m=key)
            acc[mt][nt] = __builtin_amdgcn_mfma_f32_16x16x32_bf16(bfr[nt], af[mt], acc[mt][nt], 0, 0, 0);
          else
            acc[mt][nt] = __builtin_amdgcn_mfma_f32_16x16x32_bf16(af[mt], bfr[nt], acc[mt][nt], 0, 0, 0);
        }
    }
    __syncthreads();
  }

  const int bb = (MODE == 2) ? 0 : (rowA0 / Lrows);
  const int lb = (MODE == 2) ? rowA0 : (rowA0 - bb * Lrows);
  if (MODE == 1) {
    // D[row=quad*4+r -> n(d-col)][col=l15 -> m(key)]
    for (int mt = 0; mt < 4; mt++) {
      int key = lb + rowbase + mt * 16 + l15;
      for (int nt = 0; nt < NT; nt++) {
        f32x4 v = acc[mt][nt];
        for (int r = 0; r < 4; r++) {
          int ncol = colB0 + colbase + nt * 16 + quad * 4 + r;
          float bv = bias[ncol];
          int hh = ncol >> 6, d = ncol & 63;
          ((bf16*)out)[((size_t)((bb * H + hh) * DK + d)) * LK + key] =
              __float2bfloat16(v[r] + bv);
        }
      }
    }
    return;
  }
  for (int nt = 0; nt < NT; nt++) {
    int col = colB0 + colbase + nt * 16 + l15;
    float bv = bias[col];
    int hh = col >> 6, d = col & 63;
    for (int mt = 0; mt < 4; mt++) {
      int lrow0 = lb + rowbase + mt * 16 + quad * 4;
      f32x4 v = acc[mt][nt];
      for (int r = 0; r < 4; r++) {
        float val = v[r] + bv;
        if (MODE == 0) {
          ((bf16*)out)[(((size_t)(bb * H + hh) * Lrows + lrow0 + r) << 6) + d] = __float2bfloat16(val);
        } else {
          ((float*)out)[(size_t)(lrow0 + r) * N + col] = val;
        }
      }
    }
  }
}

// Merged Q/K/V projection: one launch, 1280 blocks (K:512, V:512, Q:256).
// XCD-chunked remap: xcd = blk&7 (HW round-robin) owns a contiguous bx-range
// with ALL by values, so each A-activation panel is fetched by exactly ONE
// XCD's L2. LDS 32KB (BK=64) -> 5 blocks/CU.
__global__ __launch_bounds__(256) void proj_qkv(
    const bf16* __restrict__ kb, const bf16* __restrict__ Wkb, const float* __restrict__ bk, bf16* __restrict__ Kh,
    const bf16* __restrict__ vb, const bf16* __restrict__ Wvb, const float* __restrict__ bv, bf16* __restrict__ Vt,
    const bf16* __restrict__ qb, const bf16* __restrict__ Wqb, const float* __restrict__ bq, bf16* __restrict__ Qh) {
  __shared__ __align__(16) bf16 As[128 * 64];
  __shared__ __align__(16) bf16 Bs[128 * 64];
  const int blk = blockIdx.x;
  if (blk < 512) {
    const int xcd = blk & 7, slot = blk >> 3;
    gemm_body<0, 128>(As, Bs, kb, Wkb, bk, (void*)Kh, 8192, 1024, 1024, LK,
                      xcd * 8 + (slot & 7), slot >> 3);
  } else if (blk < 1024) {
    const int i = blk - 512, xcd = i & 7, slot = i >> 3;
    gemm_body<1, 128>(As, Bs, vb, Wvb, bv, (void*)Vt, 8192, 1024, 1024, LK,
                      xcd * 8 + (slot & 7), slot >> 3);
  } else {
    const int i = blk - 1024, xcd = i & 7, slot = i >> 3;
    gemm_body<0, 64>(As, Bs, qb, Wqb, bq, (void*)Qh, 2048, 1024, 1024, LQ,
                     xcd * 4 + (slot & 3), slot >> 2);
  }
}

// Output projection, same XCD-chunked remap. 1-D grid of 256 blocks:
// xcd = blk&7 owns 4 bx rows x all 8 by columns (bijective over 256).
__global__ __launch_bounds__(256) void gemm_o(const bf16* __restrict__ A,
                                              const bf16* __restrict__ B,
                                              const float* __restrict__ bias,
                                              float* __restrict__ out) {
  __shared__ __align__(16) bf16 As[64 * 64];
  __shared__ __align__(16) bf16 Bs[128 * 64];
  const int blk = blockIdx.x, xcd = blk & 7, slot = blk >> 3;
  gemm_body<2, 64>(As, Bs, A, B, bias, (void*)out, 2048, 1024, 1024, LQ,
                   xcd * 4 + (slot & 3), slot >> 2);
}

// ---------------- attention v9z4: attn9 structure, z=4 split-K for occupancy ----------------
// attn is grid-capped: z=2 gave 512 blocks = 2 blocks/CU = 16 waves/CU while
// LDS (36.9KB -> 4) and VGPR (~72 -> 3) allow more. z=4 -> 1024 blocks =
// 4/CU available, residency min(4,4,3)=3 blocks = 24 waves/CU (+50% TLP).
// Per-block: 512 keys = 8 chunks of 64; per-chunk structure (K/V LDS dbuf,
// rotate swizzle, 1 barrier/chunk) byte-identical to proven attn9.
// Cost: Opart/L 2x (33.5MB, fits dead qb/kb/vb region), combine 4-way.

__global__ __launch_bounds__(512) void attn9(const bf16* __restrict__ Qh,
                                             const bf16* __restrict__ Kh,
                                             const bf16* __restrict__ Vt,
                                             const short* __restrict__ pkm,
                                             const float* __restrict__ btabT,
                                             float* __restrict__ Opart,
                                             float* __restrict__ L) {
  __shared__ __align__(16) bf16 Kbuf[2][64 * 64];
  __shared__ __align__(16) bf16 Vbuf[2][64 * 64];
  __shared__ float bts[901];
  const int tid = threadIdx.x;
  const int wave = tid >> 6, lane = tid & 63;
  const int quad = lane >> 4, l15 = lane & 15;
  const int bh = blockIdx.x, b = bh >> 4, h = bh & 15;
  const int qt = blockIdx.y, z = blockIdx.z;
  const int key_base = z * 512;

  for (int i = tid; i < 901; i += 512) bts[i] = btabT[h * 901 + i];

  const int q = qt * 128 + wave * 16 + l15;  // this lane's q (B-operand col)
  short8 qf[2];
  for (int ks = 0; ks < 2; ks++)
    qf[ks] = *reinterpret_cast<const short8*>(
        Qh + ((size_t)bh * LQ + q) * DK + ks * 32 + quad * 8);

  const bf16* kbase = Kh + ((size_t)bh * LK + key_base) * DK;
  const bf16* vbase = Vt + ((size_t)bh * DK) * LK + key_base;
  const short* pkrow = pkm + ((size_t)b * LQ + q) * LK + key_base;

  // staging geometry (per wave, 1 inst each for K and V):
  // lane i -> LDS row wave*8 + (i>>3), seg i&7 (lane-linear DMA);
  // row's global seg g = ((i&7) - (i>>3)) & 7   (rotate swizzle, row%8 = i>>3)
  const int srow_off = lane >> 3;                // 0..7
  const int sseg = ((lane & 7) - srow_off) & 7;  // global segment to fetch
  const int srow = wave * 8 + srow_off;          // this lane's staged row

  f32x4 of[4];
  float denom = 0.f;
  const f32x4 zero = {0.f, 0.f, 0.f, 0.f};
  for (int dt = 0; dt < 4; dt++) of[dt] = zero;

  // ---- prologue: stage chunk 0 into buf0, prefetch pk chunk 0 ----
  g2lds16(kbase + (size_t)srow * DK + sseg * 8, &Kbuf[0][(wave * 8) * 64]);
  g2lds16(vbase + (size_t)srow * LK + sseg * 8, &Vbuf[0][(wave * 8) * 64]);
  short4v pkv[4];
  for (int nt = 0; nt < 4; nt++)
    pkv[nt] = *reinterpret_cast<const short4v*>(pkrow + nt * 16 + quad * 4);

  __syncthreads();

  for (int kc = 0; kc < 8; ++kc) {
    const int buf = kc & 1;

    // stage chunk kc+1 into buf^1 (completes at the end-of-iter barrier)
    short4v pk_n[4];
    if (kc < 7) {
      const int key1 = (kc + 1) * 64;
      g2lds16(kbase + (size_t)(key1 + srow) * DK + sseg * 8,
              &Kbuf[buf ^ 1][(wave * 8) * 64]);
      g2lds16(vbase + (size_t)srow * LK + key1 + sseg * 8,
              &Vbuf[buf ^ 1][(wave * 8) * 64]);
      for (int nt = 0; nt < 4; nt++)
        pk_n[nt] = *reinterpret_cast<const short4v*>(pkrow + key1 + nt * 16 + quad * 4);
    }

    // K frags from LDS (swizzled): row = nt*16+l15, global seg ks*4+quad
    // at LDS seg (ks*4+quad+l15)&7
    f32x4 sa[4];
    for (int nt = 0; nt < 4; nt++) sa[nt] = zero;
    for (int nt = 0; nt < 4; nt++)
      for (int ks = 0; ks < 2; ks++) {
        short8 kf = *reinterpret_cast<const short8*>(
            &Kbuf[buf][(nt * 16 + l15) * 64 + (((ks * 4 + quad + l15) & 7) << 3)]);
        sa[nt] = __builtin_amdgcn_mfma_f32_16x16x32_bf16(kf, qf[ks], sa[nt], 0, 0, 0);
      }

    // V frags from LDS (swizzled): row d = dt*16+l15, global seg nt*2+(quad>>1),
    // sub-offset (quad&1)*4 elems -> LDS seg (nt*2+(quad>>1)+l15)&7
    short4v vf[4][4];
    for (int dt = 0; dt < 4; dt++)
      for (int nt = 0; nt < 4; nt++)
        vf[dt][nt] = *reinterpret_cast<const short4v*>(
            &Vbuf[buf][(dt * 16 + l15) * 64 +
                       (((nt * 2 + (quad >> 1) + l15) & 7) << 3) + ((quad & 1) << 2)]);

    // p = exp2(s * 0.125*log2e + bts[idx])  (masked idx=900 -> -1e9 -> 0)
    short4v pf[4];
    for (int nt = 0; nt < 4; nt++) {
      float p[4];
      for (int r = 0; r < 4; r++) {
        float t = fmaf(sa[nt][r], SC2, bts[pkv[nt][r]]);
        p[r] = __builtin_amdgcn_exp2f(t);
      }
      denom += (p[0] + p[1]) + (p[2] + p[3]);
      short4v pk4;
      for (int r = 0; r < 4; r++) {
        bf16 tb = __float2bfloat16(p[r]);
        pk4[r] = *reinterpret_cast<short*>(&tb);
      }
      pf[nt] = pk4;
    }

    // PV: O^T[d][q] += V[d][key] * P^T[key][q]
    for (int dt = 0; dt < 4; dt++)
      for (int nt = 0; nt < 4; nt++)
        of[dt] = __builtin_amdgcn_mfma_f32_16x16x16bf16_1k(vf[dt][nt], pf[nt], of[dt], 0, 0, 0);

    if (kc < 7)
      for (int nt = 0; nt < 4; nt++) pkv[nt] = pk_n[nt];

    __syncthreads();  // staging of buf^1 complete; all reads of buf done
  }

  // cross-quad reduction of the denominator (keys split across quads)
  denom += __shfl_xor(denom, 16, 64);
  denom += __shfl_xor(denom, 32, 64);

  size_t rowi = ((size_t)z * 64 + bh) * LQ + q;
  float* orow = Opart + rowi * 64;
  for (int dt = 0; dt < 4; dt++)
    *reinterpret_cast<f32x4*>(orow + dt * 16 + quad * 4) = of[dt];
  if (quad == 0) L[rowi] = denom;
}

// combine the four split-K quarters -> bf16 Ob (plain sums; same fixed shift)
__global__ __launch_bounds__(256) void attn_combine(const float* __restrict__ Opart,
                                                    const float* __restrict__ L,
                                                    bf16* __restrict__ Ob) {
  int t = blockIdx.x * 256 + threadIdx.x;  // over 2M/4
  int g = t * 4;
  int row = g >> 6, d0 = g & 63;
  float l = (L[row] + L[32768 + row]) + (L[65536 + row] + L[98304 + row]);
  float4 p0 = *reinterpret_cast<const float4*>(Opart + ((size_t)row << 6) + d0);
  float4 p1 = *reinterpret_cast<const float4*>(Opart + (((size_t)row + 32768) << 6) + d0);
  float4 p2 = *reinterpret_cast<const float4*>(Opart + (((size_t)row + 65536) << 6) + d0);
  float4 p3 = *reinterpret_cast<const float4*>(Opart + (((size_t)row + 98304) << 6) + d0);
  float4 o;
  o.x = (p0.x + p1.x) + (p2.x + p3.x);
  o.y = (p0.y + p1.y) + (p2.y + p3.y);
  o.z = (p0.z + p1.z) + (p2.z + p3.z);
  o.w = (p0.w + p1.w) + (p2.w + p3.w);
  float inv = 1.f / l;
  bf16 t0 = __float2bfloat16(o.x * inv), t1 = __float2bfloat16(o.y * inv);
  bf16 t2 = __float2bfloat16(o.z * inv), t3 = __float2bfloat16(o.w * inv);
  short4 pk;
  pk.x = *reinterpret_cast<short*>(&t0);
  pk.y = *reinterpret_cast<short*>(&t1);
  pk.z = *reinterpret_cast<short*>(&t2);
  pk.w = *reinterpret_cast<short*>(&t3);
  int bh = row >> 9, qq = row & 511, b_ = bh >> 4, h = bh & 15;
  *reinterpret_cast<short4*>(Ob + ((size_t)(b_ * LQ + qq)) * DM + h * 64 + d0) = pk;
}

// ---------------- launcher ----------------

extern "C" void kernel_launch(void* const* d_in, const int* in_sizes, int n_in,
                              void* d_out, int out_size, void* d_ws, size_t ws_size,
                              hipStream_t stream) {
  const float* q = (const float*)d_in[0];
  const float* k = (const float*)d_in[1];
  const float* v = (const float*)d_in[2];
  const int* bidx = (const int*)d_in[3];
  const int* mask = (const int*)d_in[4];
  const float* Wq = (const float*)d_in[5];
  const float* bq = (const float*)d_in[6];
  const float* Wk = (const float*)d_in[7];
  const float* bk = (const float*)d_in[8];
  const float* Wv = (const float*)d_in[9];
  const float* bv = (const float*)d_in[10];
  const float* Wo = (const float*)d_in[11];
  const float* bo = (const float*)d_in[12];
  const float* btab = (const float*)d_in[13];

  char* ws = (char*)d_ws;
  bf16* qb  = (bf16*)(ws + 0);
  bf16* kb  = (bf16*)(ws + 4194304);
  bf16* vb  = (bf16*)(ws + 20971520);
  bf16* Wqb = (bf16*)(ws + 37748736);
  bf16* Wkb = (bf16*)(ws + 39845888);
  bf16* Wvb = (bf16*)(ws + 41943040);
  bf16* Wob = (bf16*)(ws + 44040192);
  bf16* Qh  = (bf16*)(ws + 46137344);
  bf16* Kh  = (bf16*)(ws + 50331648);
  bf16* Vt  = (bf16*)(ws + 67108864);
  short* pkd = (short*)(ws + 83886080);
  bf16* Ob  = (bf16*)(ws + 92274688);
  // btabT overlays the START of the Ob region: written by fused_cvt, read by
  // attn9, and only THEN overwritten by attn_combine (stream-ordered — safe).
  float* btabT = (float*)(ws + 92274688);      // 57,664 B
  // Opart/L overlay qb/kb/vb region (dead after the projection GEMMs)
  float* Opart = (float*)(ws + 0);             // 33,554,432 B (4 z-quarters)
  float* L     = (float*)(ws + 33554432);      //    524,288 B (ends 34,078,720 < 37,748,736)
  (void)ws_size; (void)in_sizes; (void)n_in; (void)out_size;

  hipLaunchKernelGGL(fused_cvt, dim3(26625), dim3(256), 0, stream,
                     q, k, v, bidx, mask, Wq, Wk, Wv, Wo, btab,
                     qb, kb, vb, Wqb, Wkb, Wvb, Wob, pkd, btabT);

  hipLaunchKernelGGL(proj_qkv, dim3(1280), dim3(256), 0, stream,
                     kb, Wkb, bk, Kh, vb, Wvb, bv, Vt, qb, Wqb, bq, Qh);

  hipLaunchKernelGGL(attn9, dim3(BSZ * H, LQ / 128, 4), dim3(512), 0, stream,
                     Qh, Kh, Vt, pkd, btabT, Opart, L);
  hipLaunchKernelGGL(attn_combine, dim3(2048), dim3(256), 0, stream,
                     Opart, L, Ob);

  hipLaunchKernelGGL(gemm_o, dim3(256), dim3(256), 0, stream,
                     Ob, Wob, bo, (float*)d_out);
}

// Round 15
// 297.282 us; speedup vs baseline: 1.0770x; 1.0252x over previous
//
#include <hip/hip_runtime.h>
#include <hip/hip_bf16.h>

#define H 16
#define DK 64
#define DM 1024
#define LQ 512
#define LK 2048
#define BSZ 4

typedef __hip_bfloat16 bf16;
typedef __attribute__((ext_vector_type(8))) short short8;
typedef __attribute__((ext_vector_type(4))) short short4v;
typedef __attribute__((ext_vector_type(4))) float f32x4;

#define LOG2E 1.44269504f
#define SC2 0.18033688f  // 0.125 * log2(e)

// ---------------- fused converts: q,k,v,Wq,Wk,Wv,Wo -> bf16; pack bias/mask; btabT ----------------
// pkd: masked entries -> sentinel index 900 (btabT[h][900] = -1e9 -> exp2 -> 0)
// btabT: per-head 901 entries, value = (btab - 10) * log2e  (exp2-domain, shift folded)

__global__ __launch_bounds__(256) void fused_cvt(
    const float* __restrict__ q, const float* __restrict__ k, const float* __restrict__ v,
    const int* __restrict__ bidx, const int* __restrict__ msk,
    const float* __restrict__ Wq, const float* __restrict__ Wk,
    const float* __restrict__ Wv, const float* __restrict__ Wo,
    const float* __restrict__ btab,
    bf16* __restrict__ qb, bf16* __restrict__ kb, bf16* __restrict__ vb,
    bf16* __restrict__ Wqb, bf16* __restrict__ Wkb, bf16* __restrict__ Wvb,
    bf16* __restrict__ Wob, short* __restrict__ pkd, float* __restrict__ btabT) {
  const int blk = blockIdx.x, tid = threadIdx.x;
  const float* src;
  bf16* dst;
  int base;
  if (blk < 2048)       { src = q;  dst = qb;  base = blk; }
  else if (blk < 10240) { src = k;  dst = kb;  base = blk - 2048; }
  else if (blk < 18432) { src = v;  dst = vb;  base = blk - 10240; }
  else if (blk < 19456) { src = Wq; dst = Wqb; base = blk - 18432; }
  else if (blk < 20480) { src = Wk; dst = Wkb; base = blk - 19456; }
  else if (blk < 21504) { src = Wv; dst = Wvb; base = blk - 20480; }
  else if (blk < 22528) { src = Wo; dst = Wob; base = blk - 21504; }
  else if (blk < 26624) {
    int i = (blk - 22528) * 1024 + tid * 4;
    int4 a = *reinterpret_cast<const int4*>(bidx + i);
    int4 m = *reinterpret_cast<const int4*>(msk + i);
    short4 r;
    r.x = m.x ? (short)a.x : (short)900;
    r.y = m.y ? (short)a.y : (short)900;
    r.z = m.z ? (short)a.z : (short)900;
    r.w = m.w ? (short)a.w : (short)900;
    *reinterpret_cast<short4*>(pkd + i) = r;
    return;
  } else {
    // bias table: transpose + fold softmax shift (-10) + log2e, append sentinel
    for (int j = tid; j < H * 901; j += 256) {
      int hh = j / 901, i = j - hh * 901;
      btabT[j] = (i == 900) ? -1e9f : (btab[i * H + hh] - 10.0f) * LOG2E;
    }
    return;
  }
  int i = base * 1024 + tid * 4;
  float4 val = *reinterpret_cast<const float4*>(src + i);
  bf16 o0 = __float2bfloat16(val.x), o1 = __float2bfloat16(val.y);
  bf16 o2 = __float2bfloat16(val.z), o3 = __float2bfloat16(val.w);
  short4 pk;
  pk.x = *reinterpret_cast<short*>(&o0);
  pk.y = *reinterpret_cast<short*>(&o1);
  pk.z = *reinterpret_cast<short*>(&o2);
  pk.w = *reinterpret_cast<short*>(&o3);
  *reinterpret_cast<short4*>(reinterpret_cast<short*>(dst) + i) = pk;
}

// ---------------- GEMM body: C[m][n] = sum_k A[m][k]*B[n][k] + bias[n] ----------------
// Single-buffered, BK=64 K-steps + rotate-swizzled staging (round-11 proven:
// bank conflicts 4.98M -> 0, total -11us): LDS[r][seg] = G[r][(seg - r)&7]
// (8 segs of 16B per 128B row). Fragment for global seg g read at LDS seg
// (g + l15)&7 -> 2 lanes/bank-group = free. Frags loaded per-K-half (ks=0,1).
// MODE 0: write bf16 head-interleaved  dst[((b*H+h)*Lrows + l)*64 + d]
// MODE 1: d-major V dst[((b*H+h)*64 + d)*LK + key] (computed transposed in-register)
// MODE 2: write f32 row-major          dst[row*N + col]
// TM: 128 (4 waves as 2x2, 64x64 each) or 64 (4 waves as 1x4, 64x32 each)

__device__ __forceinline__ void g2lds16(const bf16* g, bf16* l) {
  __builtin_amdgcn_global_load_lds(
      (__attribute__((address_space(1))) void*)(g),
      (__attribute__((address_space(3))) void*)(l), 16, 0, 0);
}

template <int MODE, int TM>
__device__ __forceinline__ void gemm_body(bf16* __restrict__ As, bf16* __restrict__ Bs,
                                          const bf16* __restrict__ A,
                                          const bf16* __restrict__ B,
                                          const float* __restrict__ bias,
                                          void* __restrict__ out,
                                          int M, int N, int K, int Lrows,
                                          int bx, int by) {
  constexpr int NT = (TM == 128) ? 4 : 2;
  const int tid = threadIdx.x;
  const int wave = tid >> 6, lane = tid & 63;
  const int quad = lane >> 4, l15 = lane & 15;
  const int rowbase = (TM == 128) ? (wave >> 1) * 64 : 0;
  const int colbase = (TM == 128) ? (wave & 1) * 64 : wave * 32;
  const int rowA0 = bx * TM, colB0 = by * 128;
  // staging geometry: inst covers 8 rows x 8 segs; lane i -> row +(i>>3),
  // LDS seg i&7; global seg ((i&7)-(i>>3))&7  (rotate swizzle, row%8 = i>>3)
  const int sro = lane >> 3;                 // 0..7
  const int sgs = ((lane & 7) - sro) & 7;    // global segment to fetch

  f32x4 acc[4][NT];
  const f32x4 zero = {0.f, 0.f, 0.f, 0.f};
  for (int mt = 0; mt < 4; mt++)
    for (int nt = 0; nt < NT; nt++) acc[mt][nt] = zero;

  for (int k0 = 0; k0 < K; k0 += 64) {
    // stage A: TM rows x 64 cols (TM/32 insts per wave)
    for (int c = 0; c < TM / 32; ++c) {
      int r = wave * (TM / 4) + c * 8;
      g2lds16(A + (size_t)(rowA0 + r + sro) * K + k0 + sgs * 8, As + r * 64);
    }
    // stage B: 128 rows x 64 cols (4 insts per wave)
    for (int c = 0; c < 4; ++c) {
      int r = wave * 32 + c * 8;
      g2lds16(B + (size_t)(colB0 + r + sro) * K + k0 + sgs * 8, Bs + r * 64);
    }
    __syncthreads();
    // two K-halves of 32; frag for global seg g=ks*4+quad at LDS seg (g+l15)&7
    for (int ks = 0; ks < 2; ++ks) {
      short8 af[4], bfr[NT];
      for (int mt = 0; mt < 4; mt++)
        af[mt] = *reinterpret_cast<const short8*>(
            As + (rowbase + mt * 16 + l15) * 64 + (((ks * 4 + quad + l15) & 7) << 3));
      for (int nt = 0; nt < NT; nt++)
        bfr[nt] = *reinterpret_cast<const short8*>(
            Bs + (colbase + nt * 16 + l15) * 64 + (((ks * 4 + quad + l15) & 7) << 3));
      for (int mt = 0; mt < 4; mt++)
        for (int nt = 0; nt < NT; nt++) {
          if (MODE == 1)  // swapped: A-op = W rows (n), B-op = act rows (m=key)
            acc[mt][nt] = __builtin_amdgcn_mfma_f32_16x16x32_bf16(bfr[nt], af[mt], acc[mt][nt], 0, 0, 0);
          else
            acc[mt][nt] = __builtin_amdgcn_mfma_f32_16x16x32_bf16(af[mt], bfr[nt], acc[mt][nt], 0, 0, 0);
        }
    }
    __syncthreads();
  }

  const int bb = (MODE == 2) ? 0 : (rowA0 / Lrows);
  const int lb = (MODE == 2) ? rowA0 : (rowA0 - bb * Lrows);
  if (MODE == 1) {
    // D[row=quad*4+r -> n(d-col)][col=l15 -> m(key)]
    for (int mt = 0; mt < 4; mt++) {
      int key = lb + rowbase + mt * 16 + l15;
      for (int nt = 0; nt < NT; nt++) {
        f32x4 v = acc[mt][nt];
        for (int r = 0; r < 4; r++) {
          int ncol = colB0 + colbase + nt * 16 + quad * 4 + r;
          float bv = bias[ncol];
          int hh = ncol >> 6, d = ncol & 63;
          ((bf16*)out)[((size_t)((bb * H + hh) * DK + d)) * LK + key] =
              __float2bfloat16(v[r] + bv);
        }
      }
    }
    return;
  }
  for (int nt = 0; nt < NT; nt++) {
    int col = colB0 + colbase + nt * 16 + l15;
    float bv = bias[col];
    int hh = col >> 6, d = col & 63;
    for (int mt = 0; mt < 4; mt++) {
      int lrow0 = lb + rowbase + mt * 16 + quad * 4;
      f32x4 v = acc[mt][nt];
      for (int r = 0; r < 4; r++) {
        float val = v[r] + bv;
        if (MODE == 0) {
          ((bf16*)out)[(((size_t)(bb * H + hh) * Lrows + lrow0 + r) << 6) + d] = __float2bfloat16(val);
        } else {
          ((float*)out)[(size_t)(lrow0 + r) * N + col] = val;
        }
      }
    }
  }
}

// Merged Q/K/V projection: one launch, 1280 blocks (K:512, V:512, Q:256).
// XCD-chunked remap: xcd = blk&7 (HW round-robin) owns a contiguous bx-range
// with ALL by values, so each A-activation panel is fetched by exactly ONE
// XCD's L2. LDS 32KB (BK=64) -> 5 blocks/CU.
__global__ __launch_bounds__(256) void proj_qkv(
    const bf16* __restrict__ kb, const bf16* __restrict__ Wkb, const float* __restrict__ bk, bf16* __restrict__ Kh,
    const bf16* __restrict__ vb, const bf16* __restrict__ Wvb, const float* __restrict__ bv, bf16* __restrict__ Vt,
    const bf16* __restrict__ qb, const bf16* __restrict__ Wqb, const float* __restrict__ bq, bf16* __restrict__ Qh) {
  __shared__ __align__(16) bf16 As[128 * 64];
  __shared__ __align__(16) bf16 Bs[128 * 64];
  const int blk = blockIdx.x;
  if (blk < 512) {
    const int xcd = blk & 7, slot = blk >> 3;
    gemm_body<0, 128>(As, Bs, kb, Wkb, bk, (void*)Kh, 8192, 1024, 1024, LK,
                      xcd * 8 + (slot & 7), slot >> 3);
  } else if (blk < 1024) {
    const int i = blk - 512, xcd = i & 7, slot = i >> 3;
    gemm_body<1, 128>(As, Bs, vb, Wvb, bv, (void*)Vt, 8192, 1024, 1024, LK,
                      xcd * 8 + (slot & 7), slot >> 3);
  } else {
    const int i = blk - 1024, xcd = i & 7, slot = i >> 3;
    gemm_body<0, 64>(As, Bs, qb, Wqb, bq, (void*)Qh, 2048, 1024, 1024, LQ,
                     xcd * 4 + (slot & 3), slot >> 2);
  }
}

// Output projection, same XCD-chunked remap. 1-D grid of 256 blocks:
// xcd = blk&7 owns 4 bx rows x all 8 by columns (bijective over 256).
__global__ __launch_bounds__(256) void gemm_o(const bf16* __restrict__ A,
                                              const bf16* __restrict__ B,
                                              const float* __restrict__ bias,
                                              float* __restrict__ out) {
  __shared__ __align__(16) bf16 As[64 * 64];
  __shared__ __align__(16) bf16 Bs[128 * 64];
  const int blk = blockIdx.x, xcd = blk & 7, slot = blk >> 3;
  gemm_body<2, 64>(As, Bs, A, B, bias, (void*)out, 2048, 1024, 1024, LQ,
                   xcd * 4 + (slot & 3), slot >> 2);
}

// ---------------- attention v9 + quad-replicated bias table ----------------
// Round-11 proven attn9 (z=2, 8 waves, 128 q rows, K/V dbuf + rotate swizzle,
// 1 barrier/chunk) with ONE change: bts[] is replicated 4x and each lane
// gathers from copy (lane>>4). Rationale (round-14 diagnostic): z=4 doubled
// occupancy with ZERO speedup -> attn is LDS-pipe-bound, not latency-bound;
// SQ_LDS_BANK_CONFLICT 7.2M cyc/dispatch (~19% of attn) and the 64-lane
// random gather into the 901-word table is the prime conflict source.
// 16 lanes/copy instead of 64 -> expected ~4x fewer collisions. Copies start
// at banks 0,5,10,15 (901 mod 32 = 5). LDS 47KB; grid caps at 2 blocks/CU
// anyway so residency unchanged. Zero extra per-element VALU (base hoisted).

__global__ __launch_bounds__(512) void attn9(const bf16* __restrict__ Qh,
                                             const bf16* __restrict__ Kh,
                                             const bf16* __restrict__ Vt,
                                             const short* __restrict__ pkm,
                                             const float* __restrict__ btabT,
                                             float* __restrict__ Opart,
                                             float* __restrict__ L) {
  __shared__ __align__(16) bf16 Kbuf[2][64 * 64];
  __shared__ __align__(16) bf16 Vbuf[2][64 * 64];
  __shared__ float bts[4 * 901];
  const int tid = threadIdx.x;
  const int wave = tid >> 6, lane = tid & 63;
  const int quad = lane >> 4, l15 = lane & 15;
  const int bh = blockIdx.x, b = bh >> 4, h = bh & 15;
  const int qt = blockIdx.y, z = blockIdx.z;
  const int key_base = z * 1024;

  for (int i = tid; i < 4 * 901; i += 512) {
    int c = i / 901;
    bts[i] = btabT[h * 901 + (i - c * 901)];
  }
  const float* btsq = bts + quad * 901;  // per-lane table copy (16 lanes/copy)

  const int q = qt * 128 + wave * 16 + l15;  // this lane's q (B-operand col)
  short8 qf[2];
  for (int ks = 0; ks < 2; ks++)
    qf[ks] = *reinterpret_cast<const short8*>(
        Qh + ((size_t)bh * LQ + q) * DK + ks * 32 + quad * 8);

  const bf16* kbase = Kh + ((size_t)bh * LK + key_base) * DK;
  const bf16* vbase = Vt + ((size_t)bh * DK) * LK + key_base;
  const short* pkrow = pkm + ((size_t)b * LQ + q) * LK + key_base;

  // staging geometry (per wave, 1 inst each for K and V):
  // lane i -> LDS row wave*8 + (i>>3), seg i&7 (lane-linear DMA);
  // row's global seg g = ((i&7) - (i>>3)) & 7   (rotate swizzle, row%8 = i>>3)
  const int srow_off = lane >> 3;                // 0..7
  const int sseg = ((lane & 7) - srow_off) & 7;  // global segment to fetch
  const int srow = wave * 8 + srow_off;          // this lane's staged row

  f32x4 of[4];
  float denom = 0.f;
  const f32x4 zero = {0.f, 0.f, 0.f, 0.f};
  for (int dt = 0; dt < 4; dt++) of[dt] = zero;

  // ---- prologue: stage chunk 0 into buf0, prefetch pk chunk 0 ----
  g2lds16(kbase + (size_t)srow * DK + sseg * 8, &Kbuf[0][(wave * 8) * 64]);
  g2lds16(vbase + (size_t)srow * LK + sseg * 8, &Vbuf[0][(wave * 8) * 64]);
  short4v pkv[4];
  for (int nt = 0; nt < 4; nt++)
    pkv[nt] = *reinterpret_cast<const short4v*>(pkrow + nt * 16 + quad * 4);

  __syncthreads();

  for (int kc = 0; kc < 16; ++kc) {
    const int buf = kc & 1;

    // stage chunk kc+1 into buf^1 (completes at the end-of-iter barrier)
    short4v pk_n[4];
    if (kc < 15) {
      const int key1 = (kc + 1) * 64;
      g2lds16(kbase + (size_t)(key1 + srow) * DK + sseg * 8,
              &Kbuf[buf ^ 1][(wave * 8) * 64]);
      g2lds16(vbase + (size_t)srow * LK + key1 + sseg * 8,
              &Vbuf[buf ^ 1][(wave * 8) * 64]);
      for (int nt = 0; nt < 4; nt++)
        pk_n[nt] = *reinterpret_cast<const short4v*>(pkrow + key1 + nt * 16 + quad * 4);
    }

    // K frags from LDS (swizzled): row = nt*16+l15, global seg ks*4+quad
    // at LDS seg (ks*4+quad+l15)&7
    f32x4 sa[4];
    for (int nt = 0; nt < 4; nt++) sa[nt] = zero;
    for (int nt = 0; nt < 4; nt++)
      for (int ks = 0; ks < 2; ks++) {
        short8 kf = *reinterpret_cast<const short8*>(
            &Kbuf[buf][(nt * 16 + l15) * 64 + (((ks * 4 + quad + l15) & 7) << 3)]);
        sa[nt] = __builtin_amdgcn_mfma_f32_16x16x32_bf16(kf, qf[ks], sa[nt], 0, 0, 0);
      }

    // V frags from LDS (swizzled): row d = dt*16+l15, global seg nt*2+(quad>>1),
    // sub-offset (quad&1)*4 elems -> LDS seg (nt*2+(quad>>1)+l15)&7
    short4v vf[4][4];
    for (int dt = 0; dt < 4; dt++)
      for (int nt = 0; nt < 4; nt++)
        vf[dt][nt] = *reinterpret_cast<const short4v*>(
            &Vbuf[buf][(dt * 16 + l15) * 64 +
                       (((nt * 2 + (quad >> 1) + l15) & 7) << 3) + ((quad & 1) << 2)]);

    // p = exp2(s * 0.125*log2e + btsq[idx])  (masked idx=900 -> -1e9 -> 0)
    short4v pf[4];
    for (int nt = 0; nt < 4; nt++) {
      float p[4];
      for (int r = 0; r < 4; r++) {
        float t = fmaf(sa[nt][r], SC2, btsq[pkv[nt][r]]);
        p[r] = __builtin_amdgcn_exp2f(t);
      }
      denom += (p[0] + p[1]) + (p[2] + p[3]);
      short4v pk4;
      for (int r = 0; r < 4; r++) {
        bf16 tb = __float2bfloat16(p[r]);
        pk4[r] = *reinterpret_cast<short*>(&tb);
      }
      pf[nt] = pk4;
    }

    // PV: O^T[d][q] += V[d][key] * P^T[key][q]
    for (int dt = 0; dt < 4; dt++)
      for (int nt = 0; nt < 4; nt++)
        of[dt] = __builtin_amdgcn_mfma_f32_16x16x16bf16_1k(vf[dt][nt], pf[nt], of[dt], 0, 0, 0);

    if (kc < 15)
      for (int nt = 0; nt < 4; nt++) pkv[nt] = pk_n[nt];

    __syncthreads();  // staging of buf^1 complete; all reads of buf done
  }

  // cross-quad reduction of the denominator (keys split across quads)
  denom += __shfl_xor(denom, 16, 64);
  denom += __shfl_xor(denom, 32, 64);

  size_t rowi = ((size_t)z * 64 + bh) * LQ + q;
  float* orow = Opart + rowi * 64;
  for (int dt = 0; dt < 4; dt++)
    *reinterpret_cast<f32x4*>(orow + dt * 16 + quad * 4) = of[dt];
  if (quad == 0) L[rowi] = denom;
}

// combine the two split-K halves -> bf16 Ob (plain sums; same fixed shift)
__global__ __launch_bounds__(256) void attn_combine(const float* __restrict__ Opart,
                                                    const float* __restrict__ L,
                                                    bf16* __restrict__ Ob) {
  int t = blockIdx.x * 256 + threadIdx.x;  // over 2M/4
  int g = t * 4;
  int row = g >> 6, d0 = g & 63;
  float l = L[row] + L[32768 + row];
  float4 o;
  float4 p0 = *reinterpret_cast<const float4*>(Opart + ((size_t)row << 6) + d0);
  float4 p1 = *reinterpret_cast<const float4*>(Opart + (((size_t)32768 + row) << 6) + d0);
  o.x = p0.x + p1.x; o.y = p0.y + p1.y; o.z = p0.z + p1.z; o.w = p0.w + p1.w;
  float inv = 1.f / l;
  bf16 t0 = __float2bfloat16(o.x * inv), t1 = __float2bfloat16(o.y * inv);
  bf16 t2 = __float2bfloat16(o.z * inv), t3 = __float2bfloat16(o.w * inv);
  short4 pk;
  pk.x = *reinterpret_cast<short*>(&t0);
  pk.y = *reinterpret_cast<short*>(&t1);
  pk.z = *reinterpret_cast<short*>(&t2);
  pk.w = *reinterpret_cast<short*>(&t3);
  int bh = row >> 9, qq = row & 511, b_ = bh >> 4, h = bh & 15;
  *reinterpret_cast<short4*>(Ob + ((size_t)(b_ * LQ + qq)) * DM + h * 64 + d0) = pk;
}

// ---------------- launcher ----------------

extern "C" void kernel_launch(void* const* d_in, const int* in_sizes, int n_in,
                              void* d_out, int out_size, void* d_ws, size_t ws_size,
                              hipStream_t stream) {
  const float* q = (const float*)d_in[0];
  const float* k = (const float*)d_in[1];
  const float* v = (const float*)d_in[2];
  const int* bidx = (const int*)d_in[3];
  const int* mask = (const int*)d_in[4];
  const float* Wq = (const float*)d_in[5];
  const float* bq = (const float*)d_in[6];
  const float* Wk = (const float*)d_in[7];
  const float* bk = (const float*)d_in[8];
  const float* Wv = (const float*)d_in[9];
  const float* bv = (const float*)d_in[10];
  const float* Wo = (const float*)d_in[11];
  const float* bo = (const float*)d_in[12];
  const float* btab = (const float*)d_in[13];

  char* ws = (char*)d_ws;
  bf16* qb  = (bf16*)(ws + 0);
  bf16* kb  = (bf16*)(ws + 4194304);
  bf16* vb  = (bf16*)(ws + 20971520);
  bf16* Wqb = (bf16*)(ws + 37748736);
  bf16* Wkb = (bf16*)(ws + 39845888);
  bf16* Wvb = (bf16*)(ws + 41943040);
  bf16* Wob = (bf16*)(ws + 44040192);
  bf16* Qh  = (bf16*)(ws + 46137344);
  bf16* Kh  = (bf16*)(ws + 50331648);
  bf16* Vt  = (bf16*)(ws + 67108864);
  short* pkd = (short*)(ws + 83886080);
  bf16* Ob  = (bf16*)(ws + 92274688);
  // btabT overlays the START of the Ob region: written by fused_cvt, read by
  // attn9, and only THEN overwritten by attn_combine (stream-ordered — safe).
  float* btabT = (float*)(ws + 92274688);      // 57,664 B
  // Opart/L overlay qb/kb region (dead after the projection GEMMs)
  float* Opart = (float*)(ws + 0);             // 16,777,216 B (2 z-halves)
  float* L     = (float*)(ws + 16777216);      //    262,144 B
  (void)ws_size; (void)in_sizes; (void)n_in; (void)out_size;

  hipLaunchKernelGGL(fused_cvt, dim3(26625), dim3(256), 0, stream,
                     q, k, v, bidx, mask, Wq, Wk, Wv, Wo, btab,
                     qb, kb, vb, Wqb, Wkb, Wvb, Wob, pkd, btabT);

  hipLaunchKernelGGL(proj_qkv, dim3(1280), dim3(256), 0, stream,
                     kb, Wkb, bk, Kh, vb, Wvb, bv, Vt, qb, Wqb, bq, Qh);

  hipLaunchKernelGGL(attn9, dim3(BSZ * H, LQ / 128, 2), dim3(512), 0, stream,
                     Qh, Kh, Vt, pkd, btabT, Opart, L);
  hipLaunchKernelGGL(attn_combine, dim3(2048), dim3(256), 0, stream,
                     Opart, L, Ob);

  hipLaunchKernelGGL(gemm_o, dim3(256), dim3(256), 0, stream,
                     Ob, Wob, bo, (float*)d_out);
}